// Round 1
// baseline (6320.384 us; speedup 1.0000x reference)
//
#include <hip/hip_runtime.h>

// Problem constants (fixed by the reference)
#define EDGES 250000
#define TRIP  1500000
#define HD    128
#define NBIL  8
#define NSR   42
#define NRAD  6

// Workspace budget (floats): 3*E*H + T*8 + 8*128*128 = 108.1M floats (433 MB)
// + ints: (E+1) + E + 2T + 256 ~ 3.5M (14 MB).  Total ~447 MB of d_ws.

__device__ __forceinline__ float silu_f(float v) {
  return v / (1.0f + __expf(-v));
}

#define GET4(v,i) ((i)==0?(v).x:((i)==1?(v).y:((i)==2?(v).z:(v).w)))

// ---------------- counting sort of triplets by idx_ji ----------------

__global__ void k_hist(const int* __restrict__ idxji, int* __restrict__ hist) {
  const int t = blockIdx.x * 256 + threadIdx.x;
  if (t < TRIP) atomicAdd(&hist[idxji[t]], 1);
}

__global__ __launch_bounds__(256) void k_scan1(const int* __restrict__ hist, int* __restrict__ blks) {
  __shared__ int sd[256];
  const int tid = threadIdx.x;
  const long base = (long)blockIdx.x * 1024 + tid * 4;
  int s = 0;
#pragma unroll
  for (int u = 0; u < 4; ++u) { const long i = base + u; if (i < EDGES) s += hist[i]; }
  sd[tid] = s; __syncthreads();
  for (int off = 128; off > 0; off >>= 1) { if (tid < off) sd[tid] += sd[tid + off]; __syncthreads(); }
  if (tid == 0) blks[blockIdx.x] = sd[0];
}

__global__ __launch_bounds__(256) void k_scan2(int* __restrict__ blks, int n) {
  __shared__ int sd[256];
  const int tid = threadIdx.x;
  const int v = (tid < n) ? blks[tid] : 0;
  sd[tid] = v; __syncthreads();
  for (int off = 1; off < 256; off <<= 1) {
    const int t = (tid >= off) ? sd[tid - off] : 0;
    __syncthreads();
    sd[tid] += t;
    __syncthreads();
  }
  if (tid < n) blks[tid] = sd[tid] - v;   // exclusive
}

// reads hist from `cursor`, writes exclusive scan to offs[] AND back into cursor[]
__global__ __launch_bounds__(256) void k_scan3(int* __restrict__ cursor, const int* __restrict__ blks,
                                               int* __restrict__ offs) {
  __shared__ int sd[256];
  const int tid = threadIdx.x;
  const long base = (long)blockIdx.x * 1024 + tid * 4;
  int v[4]; int s = 0;
#pragma unroll
  for (int u = 0; u < 4; ++u) { const long i = base + u; v[u] = (i < EDGES) ? cursor[i] : 0; s += v[u]; }
  sd[tid] = s; __syncthreads();
  for (int off = 1; off < 256; off <<= 1) {
    const int tv = (tid >= off) ? sd[tid - off] : 0;
    __syncthreads();
    sd[tid] += tv;
    __syncthreads();
  }
  int run = blks[blockIdx.x] + sd[tid] - s;
#pragma unroll
  for (int u = 0; u < 4; ++u) {
    const long i = base + u;
    if (i < EDGES) { offs[i] = run; cursor[i] = run; }
    run += v[u];
  }
  if (blockIdx.x == 0 && tid == 0) offs[EDGES] = TRIP;
}

// gkj[pos] = idx_kj[t] removes one indirection from the hot M-kernel loop;
// tpos[t] lets k_sbfh write sbf_h directly in sorted order.
__global__ void k_scatter(const int* __restrict__ idxji, const int* __restrict__ idxkj,
                          int* __restrict__ cursor, int* __restrict__ gkj, int* __restrict__ tpos) {
  const int t = blockIdx.x * 256 + threadIdx.x;
  if (t < TRIP) {
    const int e = idxji[t];
    const int pos = atomicAdd(&cursor[e], 1);
    gkj[pos] = idxkj[t];
    tpos[t] = pos;
  }
}

// ---------------- W transpose: wt[(j*128+l)*128 + i] = W[i][j][l] ----------------

__global__ void k_wt(const float* __restrict__ W, float* __restrict__ wt) {
  const int idx = blockIdx.x * 256 + threadIdx.x;
  if (idx < NBIL * HD * HD) {
    const int i = idx & (HD - 1);
    const int k = idx >> 7;          // j*128 + l
    const int j = k >> 7;
    const int l = k & (HD - 1);
    wt[idx] = W[((long)i * NBIL + j) * HD + l];
  }
}

// ---------------- sbf_h = sbf @ lin_sbf_w, written in sorted (pos) order ----------------

__global__ __launch_bounds__(256) void k_sbfh(const float* __restrict__ sbf,
    const float* __restrict__ sw, const int* __restrict__ tpos, float* __restrict__ outp) {
  __shared__ float ss[256 * NSR];
  __shared__ float wls[NSR * NBIL];
  const int tid = threadIdx.x;
  const long t0 = (long)blockIdx.x * 256;
  const long gbase = t0 * NSR;
  for (int idx = tid; idx < 256 * NSR; idx += 256) {
    const long gi = gbase + idx;
    ss[idx] = (gi < (long)TRIP * NSR) ? sbf[gi] : 0.f;
  }
  for (int idx = tid; idx < NSR * NBIL; idx += 256) wls[idx] = sw[idx];
  __syncthreads();
  const long t = t0 + tid;
  if (t < TRIP) {
    float o[NBIL] = {};
    for (int r = 0; r < NSR; ++r) {
      const float sv = ss[tid * NSR + r];
#pragma unroll
      for (int j = 0; j < NBIL; ++j) o[j] += sv * wls[r * NBIL + j];
    }
    const long p = tpos[t];
    *(float4*)(outp + p * 8) = make_float4(o[0], o[1], o[2], o[3]);
    *(float4*)(outp + p * 8 + 4) = make_float4(o[4], o[5], o[6], o[7]);
  }
}

// ---------------- edge kernel: x_ji, x_kj (dual GEMM + silu + rbf_h) ----------------

__global__ __launch_bounds__(256, 4) void k_edge(const float* __restrict__ x,
    const float* __restrict__ rbf, const float* __restrict__ rbfw,
    const float* __restrict__ wji, const float* __restrict__ bji,
    const float* __restrict__ wkj, const float* __restrict__ bkj,
    float* __restrict__ xji, float* __restrict__ xkj) {
  __shared__ float xs[32][HD + 4];
  __shared__ float rbfs[32][NRAD];
  __shared__ float rws[NRAD][HD];
  const int tid = threadIdx.x;
  const long e0 = (long)blockIdx.x * 32;
  for (int idx = tid; idx < 32 * (HD / 4); idx += 256) {
    const int el = idx >> 5; const int k4 = (idx & 31) << 2;
    const long e = e0 + el;
    float4 v = make_float4(0.f, 0.f, 0.f, 0.f);
    if (e < EDGES) v = *(const float4*)(x + e * HD + k4);
    *(float4*)&xs[el][k4] = v;
  }
  for (int idx = tid; idx < 32 * NRAD; idx += 256) {
    const int el = idx / NRAD, r = idx % NRAD;
    const long e = e0 + el;
    rbfs[el][r] = (e < EDGES) ? rbf[e * NRAD + r] : 0.f;
  }
  for (int idx = tid; idx < NRAD * HD; idx += 256) rws[idx / HD][idx % HD] = rbfw[idx];
  __syncthreads();
  const int cg = tid & 15, eg = tid >> 4;   // 16 col-groups x 16 edge-groups (2 edges each)
  const int i0 = cg * 8;
  float aj[2][8] = {}, ak[2][8] = {};
  for (int k = 0; k < HD; k += 4) {
    const float4 xv0 = *(const float4*)&xs[eg * 2 + 0][k];
    const float4 xv1 = *(const float4*)&xs[eg * 2 + 1][k];
#pragma unroll
    for (int dk = 0; dk < 4; ++dk) {
      const float4 j0 = *(const float4*)(wji + (long)(k + dk) * HD + i0);
      const float4 j1 = *(const float4*)(wji + (long)(k + dk) * HD + i0 + 4);
      const float4 q0 = *(const float4*)(wkj + (long)(k + dk) * HD + i0);
      const float4 q1 = *(const float4*)(wkj + (long)(k + dk) * HD + i0 + 4);
      const float a0 = GET4(xv0, dk), a1 = GET4(xv1, dk);
#pragma unroll
      for (int c = 0; c < 4; ++c) {
        const float wja = GET4(j0, c), wjb = GET4(j1, c);
        const float wka = GET4(q0, c), wkb = GET4(q1, c);
        aj[0][c] += a0 * wja; aj[0][c + 4] += a0 * wjb;
        aj[1][c] += a1 * wja; aj[1][c + 4] += a1 * wjb;
        ak[0][c] += a0 * wka; ak[0][c + 4] += a0 * wkb;
        ak[1][c] += a1 * wka; ak[1][c + 4] += a1 * wkb;
      }
    }
  }
  const float4 bj0 = *(const float4*)(bji + i0), bj1 = *(const float4*)(bji + i0 + 4);
  const float4 bk0 = *(const float4*)(bkj + i0), bk1 = *(const float4*)(bkj + i0 + 4);
#pragma unroll
  for (int a = 0; a < 2; ++a) {
    const int el = eg * 2 + a;
    const long e = e0 + el;
    if (e >= EDGES) continue;
    float rh[8];
#pragma unroll
    for (int c = 0; c < 8; ++c) rh[c] = 0.f;
#pragma unroll
    for (int r = 0; r < NRAD; ++r) {
      const float rv = rbfs[el][r];
#pragma unroll
      for (int c = 0; c < 8; ++c) rh[c] += rv * rws[r][i0 + c];
    }
    float oj[8], ok[8];
#pragma unroll
    for (int c = 0; c < 4; ++c) {
      oj[c]     = silu_f(aj[a][c]     + GET4(bj0, c));
      oj[c + 4] = silu_f(aj[a][c + 4] + GET4(bj1, c));
      ok[c]     = silu_f(ak[a][c]     + GET4(bk0, c)) * rh[c];
      ok[c + 4] = silu_f(ak[a][c + 4] + GET4(bk1, c)) * rh[c + 4];
    }
    *(float4*)(xji + e * HD + i0)     = make_float4(oj[0], oj[1], oj[2], oj[3]);
    *(float4*)(xji + e * HD + i0 + 4) = make_float4(oj[4], oj[5], oj[6], oj[7]);
    *(float4*)(xkj + e * HD + i0)     = make_float4(ok[0], ok[1], ok[2], ok[3]);
    *(float4*)(xkj + e * HD + i0 + 4) = make_float4(ok[4], ok[5], ok[6], ok[7]);
  }
}

// ---------------- M-kernel: per-edge outer-product accumulation + [16,1024]@[1024,128] ----------------

#define FMA16(sA, sB, xv) do { \
  m[0]  += (sA).x * (xv).x;  m[1]  += (sA).x * (xv).y; \
  m[2]  += (sA).y * (xv).x;  m[3]  += (sA).y * (xv).y; \
  m[4]  += (sA).z * (xv).x;  m[5]  += (sA).z * (xv).y; \
  m[6]  += (sA).w * (xv).x;  m[7]  += (sA).w * (xv).y; \
  m[8]  += (sB).x * (xv).x;  m[9]  += (sB).x * (xv).y; \
  m[10] += (sB).y * (xv).x;  m[11] += (sB).y * (xv).y; \
  m[12] += (sB).z * (xv).x;  m[13] += (sB).z * (xv).y; \
  m[14] += (sB).w * (xv).x;  m[15] += (sB).w * (xv).y; } while (0)

__global__ __launch_bounds__(256, 2) void k_m(const float* __restrict__ xkj,
    const float* __restrict__ sbfp, const int* __restrict__ gkj,
    const int* __restrict__ offs, const float* __restrict__ wt,
    const float* __restrict__ xji, float* __restrict__ hout) {
  __shared__ float Mt[16][1024];        // exactly 64 KB
  const int tid = threadIdx.x;
  const int lane = tid & 63;
  const int wv = tid >> 6;              // wave id, 4 waves, 4 edges each
  const long e0 = (long)blockIdx.x * 16;
  const int l2 = lane * 2;              // this lane owns cols l2, l2+1 for all j
#pragma unroll 1
  for (int es = 0; es < 4; ++es) {
    const int el = wv * 4 + es;
    const long e = e0 + el;
    float m[16];
#pragma unroll
    for (int q = 0; q < 16; ++q) m[q] = 0.f;
    const int t0 = offs[e], t1 = offs[e + 1];
    int t = t0;
    for (; t + 4 <= t1; t += 4) {       // 4-deep pipeline to hide gather latency
      const int g0 = gkj[t], g1 = gkj[t + 1], g2 = gkj[t + 2], g3 = gkj[t + 3];
      const float2 x0 = *(const float2*)(xkj + (long)g0 * HD + l2);
      const float2 x1 = *(const float2*)(xkj + (long)g1 * HD + l2);
      const float2 x2 = *(const float2*)(xkj + (long)g2 * HD + l2);
      const float2 x3 = *(const float2*)(xkj + (long)g3 * HD + l2);
      const float4 sa0 = *(const float4*)(sbfp + (long)t * 8);
      const float4 sb0 = *(const float4*)(sbfp + (long)t * 8 + 4);
      const float4 sa1 = *(const float4*)(sbfp + (long)(t + 1) * 8);
      const float4 sb1 = *(const float4*)(sbfp + (long)(t + 1) * 8 + 4);
      const float4 sa2 = *(const float4*)(sbfp + (long)(t + 2) * 8);
      const float4 sb2 = *(const float4*)(sbfp + (long)(t + 2) * 8 + 4);
      const float4 sa3 = *(const float4*)(sbfp + (long)(t + 3) * 8);
      const float4 sb3 = *(const float4*)(sbfp + (long)(t + 3) * 8 + 4);
      FMA16(sa0, sb0, x0);
      FMA16(sa1, sb1, x1);
      FMA16(sa2, sb2, x2);
      FMA16(sa3, sb3, x3);
    }
    for (; t < t1; ++t) {
      const int g = gkj[t];
      const float2 xv = *(const float2*)(xkj + (long)g * HD + l2);
      const float4 sa = *(const float4*)(sbfp + (long)t * 8);
      const float4 sb = *(const float4*)(sbfp + (long)t * 8 + 4);
      FMA16(sa, sb, xv);
    }
#pragma unroll
    for (int j = 0; j < 8; ++j)
      *(float2*)&Mt[el][j * 128 + l2] = make_float2(m[2 * j], m[2 * j + 1]);
  }
  __syncthreads();
  // phase B: agg = M @ wt ; h = x_ji + agg
  const int cg = tid & 15, er = tid >> 4;   // 16 cols-of-8 x 16 edges
  const int i0 = cg * 8;
  float acc[8] = {};
  for (int kk = 0; kk < 1024; kk += 4) {
    const float4 mv = *(const float4*)&Mt[er][kk];
#pragma unroll
    for (int dk = 0; dk < 4; ++dk) {
      const float4 w0 = *(const float4*)(wt + (long)(kk + dk) * HD + i0);
      const float4 w1 = *(const float4*)(wt + (long)(kk + dk) * HD + i0 + 4);
      const float md = GET4(mv, dk);
      acc[0] += md * w0.x; acc[1] += md * w0.y; acc[2] += md * w0.z; acc[3] += md * w0.w;
      acc[4] += md * w1.x; acc[5] += md * w1.y; acc[6] += md * w1.z; acc[7] += md * w1.w;
    }
  }
  const long e = e0 + er;
  const float4 xa = *(const float4*)(xji + e * HD + i0);
  const float4 xb = *(const float4*)(xji + e * HD + i0 + 4);
  *(float4*)(hout + e * HD + i0)     = make_float4(acc[0] + xa.x, acc[1] + xa.y, acc[2] + xa.z, acc[3] + xa.w);
  *(float4*)(hout + e * HD + i0 + 4) = make_float4(acc[4] + xb.x, acc[5] + xb.y, acc[6] + xb.z, acc[7] + xb.w);
}

// ---------------- generic [E,128]@[128,128] + bias + silu (+add) ----------------

template<bool ADD>
__global__ __launch_bounds__(256, 4) void k_gemm(const float* __restrict__ in,
    const float* __restrict__ w, const float* __restrict__ bias,
    const float* __restrict__ addsrc, float* __restrict__ out) {
  __shared__ float xs[64][HD + 4];
  const int tid = threadIdx.x;
  const long e0 = (long)blockIdx.x * 64;
  for (int idx = tid; idx < 64 * (HD / 4); idx += 256) {
    const int el = idx >> 5; const int k4 = (idx & 31) << 2;
    const long e = e0 + el;
    float4 v = make_float4(0.f, 0.f, 0.f, 0.f);
    if (e < EDGES) v = *(const float4*)(in + e * HD + k4);
    *(float4*)&xs[el][k4] = v;
  }
  __syncthreads();
  const int cg = tid & 15, eg = tid >> 4;   // 16 col-groups x 16 edge-groups (4 edges each)
  const int i0 = cg * 8;
  float acc[4][8] = {};
  for (int k = 0; k < HD; k += 4) {
    const float4 xv0 = *(const float4*)&xs[eg * 4 + 0][k];
    const float4 xv1 = *(const float4*)&xs[eg * 4 + 1][k];
    const float4 xv2 = *(const float4*)&xs[eg * 4 + 2][k];
    const float4 xv3 = *(const float4*)&xs[eg * 4 + 3][k];
#pragma unroll
    for (int dk = 0; dk < 4; ++dk) {
      const float4 w0 = *(const float4*)(w + (long)(k + dk) * HD + i0);
      const float4 w1 = *(const float4*)(w + (long)(k + dk) * HD + i0 + 4);
      const float a0 = GET4(xv0, dk), a1 = GET4(xv1, dk), a2 = GET4(xv2, dk), a3 = GET4(xv3, dk);
#pragma unroll
      for (int c = 0; c < 4; ++c) {
        const float wa = GET4(w0, c), wb = GET4(w1, c);
        acc[0][c] += a0 * wa; acc[0][c + 4] += a0 * wb;
        acc[1][c] += a1 * wa; acc[1][c + 4] += a1 * wb;
        acc[2][c] += a2 * wa; acc[2][c + 4] += a2 * wb;
        acc[3][c] += a3 * wa; acc[3][c + 4] += a3 * wb;
      }
    }
  }
  const float4 b0 = *(const float4*)(bias + i0);
  const float4 b1 = *(const float4*)(bias + i0 + 4);
#pragma unroll
  for (int a = 0; a < 4; ++a) {
    const long e = e0 + eg * 4 + a;
    if (e >= EDGES) continue;
    float o[8];
#pragma unroll
    for (int c = 0; c < 4; ++c) {
      o[c]     = silu_f(acc[a][c]     + GET4(b0, c));
      o[c + 4] = silu_f(acc[a][c + 4] + GET4(b1, c));
    }
    if (ADD) {
      const float4 ad0 = *(const float4*)(addsrc + e * HD + i0);
      const float4 ad1 = *(const float4*)(addsrc + e * HD + i0 + 4);
#pragma unroll
      for (int c = 0; c < 4; ++c) { o[c] += GET4(ad0, c); o[c + 4] += GET4(ad1, c); }
    }
    *(float4*)(out + e * HD + i0)     = make_float4(o[0], o[1], o[2], o[3]);
    *(float4*)(out + e * HD + i0 + 4) = make_float4(o[4], o[5], o[6], o[7]);
  }
}

// ---------------- launch ----------------

extern "C" void kernel_launch(void* const* d_in, const int* in_sizes, int n_in,
                              void* d_out, int out_size, void* d_ws, size_t ws_size,
                              hipStream_t stream) {
  const float* x         = (const float*)d_in[0];
  const float* rbf       = (const float*)d_in[1];
  const float* sbf       = (const float*)d_in[2];
  const int*   idx_kj    = (const int*)d_in[3];
  const int*   idx_ji    = (const int*)d_in[4];
  const float* lin_rbf_w = (const float*)d_in[5];
  const float* lin_sbf_w = (const float*)d_in[6];
  const float* lin_kj_w  = (const float*)d_in[7];
  const float* lin_kj_b  = (const float*)d_in[8];
  const float* lin_ji_w  = (const float*)d_in[9];
  const float* lin_ji_b  = (const float*)d_in[10];
  const float* Wtri      = (const float*)d_in[11];
  const float* rb_w1 = (const float*)d_in[12];
  const float* rb_b1 = (const float*)d_in[13];
  const float* rb_w2 = (const float*)d_in[14];
  const float* rb_b2 = (const float*)d_in[15];
  const float* lin_w = (const float*)d_in[16];
  const float* lin_b = (const float*)d_in[17];
  const float* ra1_w1 = (const float*)d_in[18];
  const float* ra1_b1 = (const float*)d_in[19];
  const float* ra1_w2 = (const float*)d_in[20];
  const float* ra1_b2 = (const float*)d_in[21];
  const float* ra2_w1 = (const float*)d_in[22];
  const float* ra2_b1 = (const float*)d_in[23];
  const float* ra2_w2 = (const float*)d_in[24];
  const float* ra2_b2 = (const float*)d_in[25];
  const float* lin_out_w = (const float*)d_in[26];
  const float* lin_out_b = (const float*)d_in[27];
  float* outp = (float*)d_out;

  const size_t EH = (size_t)EDGES * HD;
  float* buf0 = (float*)d_ws;                    // x_ji, later ping-pong
  float* buf1 = buf0 + EH;                       // x_kj, later ping-pong
  float* buf2 = buf1 + EH;                       // h,    later ping-pong
  float* sbfp = buf2 + EH;                       // sbf_h in sorted order [T,8]
  float* wt   = sbfp + (size_t)TRIP * NBIL;      // transposed W [1024,128]
  int* offs   = (int*)(wt + (size_t)NBIL * HD * HD);  // E+1
  int* cursor = offs + (EDGES + 1);              // E (hist, then cursor)
  int* gkj    = cursor + EDGES;                  // T
  int* tpos   = gkj + TRIP;                      // T
  int* blks   = tpos + TRIP;                     // 256

  hipMemsetAsync(cursor, 0, EDGES * sizeof(int), stream);
  const int TB  = (TRIP + 255) / 256;
  const int SCB = (EDGES + 1023) / 1024;
  k_hist<<<TB, 256, 0, stream>>>(idx_ji, cursor);
  k_scan1<<<SCB, 256, 0, stream>>>(cursor, blks);
  k_scan2<<<1, 256, 0, stream>>>(blks, SCB);
  k_scan3<<<SCB, 256, 0, stream>>>(cursor, blks, offs);
  k_scatter<<<TB, 256, 0, stream>>>(idx_ji, idx_kj, cursor, gkj, tpos);
  k_wt<<<(NBIL * HD * HD + 255) / 256, 256, 0, stream>>>(Wtri, wt);
  k_sbfh<<<TB, 256, 0, stream>>>(sbf, lin_sbf_w, tpos, sbfp);
  k_edge<<<(EDGES + 31) / 32, 256, 0, stream>>>(x, rbf, lin_rbf_w,
      lin_ji_w, lin_ji_b, lin_kj_w, lin_kj_b, buf0, buf1);
  k_m<<<EDGES / 16, 256, 0, stream>>>(buf1, sbfp, gkj, offs, wt, buf0, buf2);
  const int GB = (EDGES + 63) / 64;
  k_gemm<false><<<GB, 256, 0, stream>>>(buf2, rb_w1, rb_b1, nullptr, buf1);  // t1
  k_gemm<true ><<<GB, 256, 0, stream>>>(buf1, rb_w2, rb_b2, buf2, buf0);     // h  = h + silu(..)
  k_gemm<true ><<<GB, 256, 0, stream>>>(buf0, lin_w, lin_b, x, buf2);        // h2 = silu(..) + x
  k_gemm<false><<<GB, 256, 0, stream>>>(buf2, ra1_w1, ra1_b1, nullptr, buf1);
  k_gemm<true ><<<GB, 256, 0, stream>>>(buf1, ra1_w2, ra1_b2, buf2, buf0);   // h3
  k_gemm<false><<<GB, 256, 0, stream>>>(buf0, ra2_w1, ra2_b1, nullptr, buf1);
  k_gemm<true ><<<GB, 256, 0, stream>>>(buf1, ra2_w2, ra2_b2, buf0, buf2);   // h4
  k_gemm<false><<<GB, 256, 0, stream>>>(buf2, lin_out_w, lin_out_b, nullptr, outp);
}

// Round 3
// 4202.727 us; speedup vs baseline: 1.5039x; 1.5039x over previous
//
#include <hip/hip_runtime.h>

// Problem constants (fixed by the reference)
#define EDGES 250000
#define TRIP  1500000
#define HD    128
#define NBIL  8
#define NSR   42
#define NRAD  6

__device__ __forceinline__ float silu_f(float v) {
  return v / (1.0f + __expf(-v));
}

#define GET4(v,i) ((i)==0?(v).x:((i)==1?(v).y:((i)==2?(v).z:(v).w)))

// ---------------- counting sort of triplets by idx_ji ----------------

__global__ void k_hist(const int* __restrict__ idxji, int* __restrict__ hist) {
  const int t = blockIdx.x * 256 + threadIdx.x;
  if (t < TRIP) atomicAdd(&hist[idxji[t]], 1);
}

__global__ __launch_bounds__(256) void k_scan1(const int* __restrict__ hist, int* __restrict__ blks) {
  __shared__ int sd[256];
  const int tid = threadIdx.x;
  const long base = (long)blockIdx.x * 1024 + tid * 4;
  int s = 0;
#pragma unroll
  for (int u = 0; u < 4; ++u) { const long i = base + u; if (i < EDGES) s += hist[i]; }
  sd[tid] = s; __syncthreads();
  for (int off = 128; off > 0; off >>= 1) { if (tid < off) sd[tid] += sd[tid + off]; __syncthreads(); }
  if (tid == 0) blks[blockIdx.x] = sd[0];
}

__global__ __launch_bounds__(256) void k_scan2(int* __restrict__ blks, int n) {
  __shared__ int sd[256];
  const int tid = threadIdx.x;
  const int v = (tid < n) ? blks[tid] : 0;
  sd[tid] = v; __syncthreads();
  for (int off = 1; off < 256; off <<= 1) {
    const int t = (tid >= off) ? sd[tid - off] : 0;
    __syncthreads();
    sd[tid] += t;
    __syncthreads();
  }
  if (tid < n) blks[tid] = sd[tid] - v;   // exclusive
}

// reads hist from `cursor`, writes exclusive scan to offs[] AND back into cursor[]
__global__ __launch_bounds__(256) void k_scan3(int* __restrict__ cursor, const int* __restrict__ blks,
                                               int* __restrict__ offs) {
  __shared__ int sd[256];
  const int tid = threadIdx.x;
  const long base = (long)blockIdx.x * 1024 + tid * 4;
  int v[4]; int s = 0;
#pragma unroll
  for (int u = 0; u < 4; ++u) { const long i = base + u; v[u] = (i < EDGES) ? cursor[i] : 0; s += v[u]; }
  sd[tid] = s; __syncthreads();
  for (int off = 1; off < 256; off <<= 1) {
    const int tv = (tid >= off) ? sd[tid - off] : 0;
    __syncthreads();
    sd[tid] += tv;
    __syncthreads();
  }
  int run = blks[blockIdx.x] + sd[tid] - s;
#pragma unroll
  for (int u = 0; u < 4; ++u) {
    const long i = base + u;
    if (i < EDGES) { offs[i] = run; cursor[i] = run; }
    run += v[u];
  }
  if (blockIdx.x == 0 && tid == 0) offs[EDGES] = TRIP;
}

__global__ void k_scatter(const int* __restrict__ idxji, const int* __restrict__ idxkj,
                          int* __restrict__ cursor, int* __restrict__ gkj, int* __restrict__ tpos) {
  const int t = blockIdx.x * 256 + threadIdx.x;
  if (t < TRIP) {
    const int e = idxji[t];
    const int pos = atomicAdd(&cursor[e], 1);
    gkj[pos] = idxkj[t];
    tpos[t] = pos;
  }
}

// ---------------- W transpose: wt[(j*128+l)*128 + i] = W[i][j][l] ----------------

__global__ void k_wt(const float* __restrict__ W, float* __restrict__ wt) {
  const int idx = blockIdx.x * 256 + threadIdx.x;
  if (idx < NBIL * HD * HD) {
    const int i = idx & (HD - 1);
    const int k = idx >> 7;          // j*128 + l
    const int j = k >> 7;
    const int l = k & (HD - 1);
    wt[idx] = W[((long)i * NBIL + j) * HD + l];
  }
}

// ---------------- sbf_h = sbf @ lin_sbf_w, written in sorted (pos) order ----------------

__global__ __launch_bounds__(256) void k_sbfh(const float* __restrict__ sbf,
    const float* __restrict__ sw, const int* __restrict__ tpos, float* __restrict__ outp) {
  __shared__ float ss[256 * NSR];
  __shared__ float wls[NSR * NBIL];
  const int tid = threadIdx.x;
  const long t0 = (long)blockIdx.x * 256;
  const long gbase = t0 * NSR;
  for (int idx = tid; idx < 256 * NSR; idx += 256) {
    const long gi = gbase + idx;
    ss[idx] = (gi < (long)TRIP * NSR) ? sbf[gi] : 0.f;
  }
  for (int idx = tid; idx < NSR * NBIL; idx += 256) wls[idx] = sw[idx];
  __syncthreads();
  const long t = t0 + tid;
  if (t < TRIP) {
    float o[NBIL] = {};
    for (int r = 0; r < NSR; ++r) {
      const float sv = ss[tid * NSR + r];
#pragma unroll
      for (int j = 0; j < NBIL; ++j) o[j] += sv * wls[r * NBIL + j];
    }
    const long p = tpos[t];
    *(float4*)(outp + p * 8) = make_float4(o[0], o[1], o[2], o[3]);
    *(float4*)(outp + p * 8 + 4) = make_float4(o[4], o[5], o[6], o[7]);
  }
}

// ---------------- edge kernel: x_ji, x_kj (dual GEMM + silu + rbf_h) ----------------

__global__ __launch_bounds__(256, 4) void k_edge(const float* __restrict__ x,
    const float* __restrict__ rbf, const float* __restrict__ rbfw,
    const float* __restrict__ wji, const float* __restrict__ bji,
    const float* __restrict__ wkj, const float* __restrict__ bkj,
    float* __restrict__ xji, float* __restrict__ xkj) {
  __shared__ float xs[32][HD + 4];
  __shared__ float rbfs[32][NRAD];
  __shared__ float rws[NRAD][HD];
  const int tid = threadIdx.x;
  const long e0 = (long)blockIdx.x * 32;
  for (int idx = tid; idx < 32 * (HD / 4); idx += 256) {
    const int el = idx >> 5; const int k4 = (idx & 31) << 2;
    const long e = e0 + el;
    float4 v = make_float4(0.f, 0.f, 0.f, 0.f);
    if (e < EDGES) v = *(const float4*)(x + e * HD + k4);
    *(float4*)&xs[el][k4] = v;
  }
  for (int idx = tid; idx < 32 * NRAD; idx += 256) {
    const int el = idx / NRAD, r = idx % NRAD;
    const long e = e0 + el;
    rbfs[el][r] = (e < EDGES) ? rbf[e * NRAD + r] : 0.f;
  }
  for (int idx = tid; idx < NRAD * HD; idx += 256) rws[idx / HD][idx % HD] = rbfw[idx];
  __syncthreads();
  const int cg = tid & 15, eg = tid >> 4;   // 16 col-groups x 16 edge-groups (2 edges each)
  const int i0 = cg * 8;
  float aj[2][8] = {}, ak[2][8] = {};
  for (int k = 0; k < HD; k += 4) {
    const float4 xv0 = *(const float4*)&xs[eg * 2 + 0][k];
    const float4 xv1 = *(const float4*)&xs[eg * 2 + 1][k];
#pragma unroll
    for (int dk = 0; dk < 4; ++dk) {
      const float4 j0 = *(const float4*)(wji + (long)(k + dk) * HD + i0);
      const float4 j1 = *(const float4*)(wji + (long)(k + dk) * HD + i0 + 4);
      const float4 q0 = *(const float4*)(wkj + (long)(k + dk) * HD + i0);
      const float4 q1 = *(const float4*)(wkj + (long)(k + dk) * HD + i0 + 4);
      const float a0 = GET4(xv0, dk), a1 = GET4(xv1, dk);
#pragma unroll
      for (int c = 0; c < 4; ++c) {
        const float wja = GET4(j0, c), wjb = GET4(j1, c);
        const float wka = GET4(q0, c), wkb = GET4(q1, c);
        aj[0][c] += a0 * wja; aj[0][c + 4] += a0 * wjb;
        aj[1][c] += a1 * wja; aj[1][c + 4] += a1 * wjb;
        ak[0][c] += a0 * wka; ak[0][c + 4] += a0 * wkb;
        ak[1][c] += a1 * wka; ak[1][c + 4] += a1 * wkb;
      }
    }
  }
  const float4 bj0 = *(const float4*)(bji + i0), bj1 = *(const float4*)(bji + i0 + 4);
  const float4 bk0 = *(const float4*)(bkj + i0), bk1 = *(const float4*)(bkj + i0 + 4);
#pragma unroll
  for (int a = 0; a < 2; ++a) {
    const int el = eg * 2 + a;
    const long e = e0 + el;
    if (e >= EDGES) continue;
    float rh[8];
#pragma unroll
    for (int c = 0; c < 8; ++c) rh[c] = 0.f;
#pragma unroll
    for (int r = 0; r < NRAD; ++r) {
      const float rv = rbfs[el][r];
#pragma unroll
      for (int c = 0; c < 8; ++c) rh[c] += rv * rws[r][i0 + c];
    }
    float oj[8], ok[8];
#pragma unroll
    for (int c = 0; c < 4; ++c) {
      oj[c]     = silu_f(aj[a][c]     + GET4(bj0, c));
      oj[c + 4] = silu_f(aj[a][c + 4] + GET4(bj1, c));
      ok[c]     = silu_f(ak[a][c]     + GET4(bk0, c)) * rh[c];
      ok[c + 4] = silu_f(ak[a][c + 4] + GET4(bk1, c)) * rh[c + 4];
    }
    *(float4*)(xji + e * HD + i0)     = make_float4(oj[0], oj[1], oj[2], oj[3]);
    *(float4*)(xji + e * HD + i0 + 4) = make_float4(oj[4], oj[5], oj[6], oj[7]);
    *(float4*)(xkj + e * HD + i0)     = make_float4(ok[0], ok[1], ok[2], ok[3]);
    *(float4*)(xkj + e * HD + i0 + 4) = make_float4(ok[4], ok[5], ok[6], ok[7]);
  }
}

// ---------------- outer-product accumulation ----------------

#define FMA16(sA, sB, xv) do { \
  m[0]  += (sA).x * (xv).x;  m[1]  += (sA).x * (xv).y; \
  m[2]  += (sA).y * (xv).x;  m[3]  += (sA).y * (xv).y; \
  m[4]  += (sA).z * (xv).x;  m[5]  += (sA).z * (xv).y; \
  m[6]  += (sA).w * (xv).x;  m[7]  += (sA).w * (xv).y; \
  m[8]  += (sB).x * (xv).x;  m[9]  += (sB).x * (xv).y; \
  m[10] += (sB).y * (xv).x;  m[11] += (sB).y * (xv).y; \
  m[12] += (sB).z * (xv).x;  m[13] += (sB).z * (xv).y; \
  m[14] += (sB).w * (xv).x;  m[15] += (sB).w * (xv).y; } while (0)

#define ACCUM_SEGMENT(t0, t1) \
    int t = (t0); \
    for (; t + 4 <= (t1); t += 4) { \
      const int g0 = gkj[t], g1 = gkj[t + 1], g2 = gkj[t + 2], g3 = gkj[t + 3]; \
      const float2 x0 = *(const float2*)(xkj + (long)g0 * HD + l2); \
      const float2 x1 = *(const float2*)(xkj + (long)g1 * HD + l2); \
      const float2 x2 = *(const float2*)(xkj + (long)g2 * HD + l2); \
      const float2 x3 = *(const float2*)(xkj + (long)g3 * HD + l2); \
      const float4 sa0 = *(const float4*)(sbfp + (long)t * 8); \
      const float4 sb0 = *(const float4*)(sbfp + (long)t * 8 + 4); \
      const float4 sa1 = *(const float4*)(sbfp + (long)(t + 1) * 8); \
      const float4 sb1 = *(const float4*)(sbfp + (long)(t + 1) * 8 + 4); \
      const float4 sa2 = *(const float4*)(sbfp + (long)(t + 2) * 8); \
      const float4 sb2 = *(const float4*)(sbfp + (long)(t + 2) * 8 + 4); \
      const float4 sa3 = *(const float4*)(sbfp + (long)(t + 3) * 8); \
      const float4 sb3 = *(const float4*)(sbfp + (long)(t + 3) * 8 + 4); \
      FMA16(sa0, sb0, x0); \
      FMA16(sa1, sb1, x1); \
      FMA16(sa2, sb2, x2); \
      FMA16(sa3, sb3, x3); \
    } \
    for (; t < (t1); ++t) { \
      const int g = gkj[t]; \
      const float2 xv = *(const float2*)(xkj + (long)g * HD + l2); \
      const float4 sa = *(const float4*)(sbfp + (long)t * 8); \
      const float4 sb = *(const float4*)(sbfp + (long)t * 8 + 4); \
      FMA16(sa, sb, xv); \
    }

// k_mA: M[er][j*128+l] = sum over segment of sbf_h[t][j]*xk[t][l]; 1 wave per edge,
// no LDS -> high occupancy, gather latency hidden by ~20 waves/CU.
__global__ __launch_bounds__(256, 4) void k_mA(const float* __restrict__ xkj,
    const float* __restrict__ sbfp, const int* __restrict__ gkj,
    const int* __restrict__ offs, float* __restrict__ M, int e0chunk, int ecount) {
  const int tid = threadIdx.x;
  const int lane = tid & 63;
  const int wv = tid >> 6;
  const int er = blockIdx.x * 4 + wv;
  if (er >= ecount) return;
  const long e = (long)e0chunk + er;
  const int l2 = lane * 2;
  float m[16];
#pragma unroll
  for (int q = 0; q < 16; ++q) m[q] = 0.f;
  const int t0 = offs[e], t1 = offs[e + 1];
  { ACCUM_SEGMENT(t0, t1) }
#pragma unroll
  for (int j = 0; j < 8; ++j)
    *(float2*)(M + (long)er * 1024 + j * 128 + l2) = make_float2(m[2 * j], m[2 * j + 1]);
}

// k_mB: h = x_ji + M @ wt   ([ecount,1024] @ [1024,128])
__global__ __launch_bounds__(256, 4) void k_mB(const float* __restrict__ M,
    const float* __restrict__ wt, const float* __restrict__ xji,
    float* __restrict__ hout, int e0chunk, int ecount) {
  __shared__ float ms[64][68];
  const int tid = threadIdx.x;
  const int rbase = blockIdx.x * 64;
  const int cg = tid & 15, eg = tid >> 4;
  const int i0 = cg * 8;
  float acc[4][8] = {};
  for (int kc = 0; kc < 16; ++kc) {
    __syncthreads();
    for (int idx = tid; idx < 64 * 16; idx += 256) {
      const int r = idx >> 4, c4 = (idx & 15) << 2;
      const int row = rbase + r;
      float4 v = make_float4(0.f, 0.f, 0.f, 0.f);
      if (row < ecount) v = *(const float4*)(M + (long)row * 1024 + kc * 64 + c4);
      *(float4*)&ms[r][c4] = v;
    }
    __syncthreads();
    for (int kk = 0; kk < 64; kk += 4) {
      const float4 a0 = *(const float4*)&ms[eg * 4 + 0][kk];
      const float4 a1 = *(const float4*)&ms[eg * 4 + 1][kk];
      const float4 a2 = *(const float4*)&ms[eg * 4 + 2][kk];
      const float4 a3 = *(const float4*)&ms[eg * 4 + 3][kk];
#pragma unroll
      for (int dk = 0; dk < 4; ++dk) {
        const long kg = (long)kc * 64 + kk + dk;
        const float4 w0 = *(const float4*)(wt + kg * HD + i0);
        const float4 w1 = *(const float4*)(wt + kg * HD + i0 + 4);
        const float v0 = GET4(a0, dk), v1 = GET4(a1, dk), v2 = GET4(a2, dk), v3 = GET4(a3, dk);
#pragma unroll
        for (int c = 0; c < 4; ++c) {
          const float wa = GET4(w0, c), wb = GET4(w1, c);
          acc[0][c] += v0 * wa; acc[0][c + 4] += v0 * wb;
          acc[1][c] += v1 * wa; acc[1][c + 4] += v1 * wb;
          acc[2][c] += v2 * wa; acc[2][c + 4] += v2 * wb;
          acc[3][c] += v3 * wa; acc[3][c + 4] += v3 * wb;
        }
      }
    }
  }
#pragma unroll
  for (int a = 0; a < 4; ++a) {
    const int row = rbase + eg * 4 + a;
    if (row >= ecount) continue;
    const long e = (long)e0chunk + row;
    const float4 xa = *(const float4*)(xji + e * HD + i0);
    const float4 xb = *(const float4*)(xji + e * HD + i0 + 4);
    *(float4*)(hout + e * HD + i0)     = make_float4(acc[a][0] + xa.x, acc[a][1] + xa.y,
                                                     acc[a][2] + xa.z, acc[a][3] + xa.w);
    *(float4*)(hout + e * HD + i0 + 4) = make_float4(acc[a][4] + xb.x, acc[a][5] + xb.y,
                                                     acc[a][6] + xb.z, acc[a][7] + xb.w);
  }
}

// ---------------- fallback fused M-kernel (used only if d_ws too small) ----------------

__global__ __launch_bounds__(256, 2) void k_m(const float* __restrict__ xkj,
    const float* __restrict__ sbfp, const int* __restrict__ gkj,
    const int* __restrict__ offs, const float* __restrict__ wt,
    const float* __restrict__ xji, float* __restrict__ hout) {
  __shared__ float Mt[16][1024];
  const int tid = threadIdx.x;
  const int lane = tid & 63;
  const int wv = tid >> 6;
  const long e0 = (long)blockIdx.x * 16;
  const int l2 = lane * 2;
#pragma unroll 1
  for (int es = 0; es < 4; ++es) {
    const int el = wv * 4 + es;
    const long e = e0 + el;
    float m[16];
#pragma unroll
    for (int q = 0; q < 16; ++q) m[q] = 0.f;
    const int t0 = offs[e], t1 = offs[e + 1];
    { ACCUM_SEGMENT(t0, t1) }
#pragma unroll
    for (int j = 0; j < 8; ++j)
      *(float2*)&Mt[el][j * 128 + l2] = make_float2(m[2 * j], m[2 * j + 1]);
  }
  __syncthreads();
  const int cg = tid & 15, er = tid >> 4;
  const int i0 = cg * 8;
  float acc[8] = {};
  for (int kk = 0; kk < 1024; kk += 4) {
    const float4 mv = *(const float4*)&Mt[er][kk];
#pragma unroll
    for (int dk = 0; dk < 4; ++dk) {
      const float4 w0 = *(const float4*)(wt + (long)(kk + dk) * HD + i0);
      const float4 w1 = *(const float4*)(wt + (long)(kk + dk) * HD + i0 + 4);
      const float md = GET4(mv, dk);
      acc[0] += md * w0.x; acc[1] += md * w0.y; acc[2] += md * w0.z; acc[3] += md * w0.w;
      acc[4] += md * w1.x; acc[5] += md * w1.y; acc[6] += md * w1.z; acc[7] += md * w1.w;
    }
  }
  const long e = e0 + er;
  const float4 xa = *(const float4*)(xji + e * HD + i0);
  const float4 xb = *(const float4*)(xji + e * HD + i0 + 4);
  *(float4*)(hout + e * HD + i0)     = make_float4(acc[0] + xa.x, acc[1] + xa.y, acc[2] + xa.z, acc[3] + xa.w);
  *(float4*)(hout + e * HD + i0 + 4) = make_float4(acc[4] + xb.x, acc[5] + xb.y, acc[6] + xb.z, acc[7] + xb.w);
}

// ---------------- generic [E,128]@[128,128] + bias + silu (+add) ----------------

template<bool ADD>
__global__ __launch_bounds__(256, 4) void k_gemm(const float* __restrict__ in,
    const float* __restrict__ w, const float* __restrict__ bias,
    const float* __restrict__ addsrc, float* __restrict__ out) {
  __shared__ float xs[64][HD + 4];
  const int tid = threadIdx.x;
  const long e0 = (long)blockIdx.x * 64;
  for (int idx = tid; idx < 64 * (HD / 4); idx += 256) {
    const int el = idx >> 5; const int k4 = (idx & 31) << 2;
    const long e = e0 + el;
    float4 v = make_float4(0.f, 0.f, 0.f, 0.f);
    if (e < EDGES) v = *(const float4*)(in + e * HD + k4);
    *(float4*)&xs[el][k4] = v;
  }
  __syncthreads();
  const int cg = tid & 15, eg = tid >> 4;
  const int i0 = cg * 8;
  float acc[4][8] = {};
  for (int k = 0; k < HD; k += 4) {
    const float4 xv0 = *(const float4*)&xs[eg * 4 + 0][k];
    const float4 xv1 = *(const float4*)&xs[eg * 4 + 1][k];
    const float4 xv2 = *(const float4*)&xs[eg * 4 + 2][k];
    const float4 xv3 = *(const float4*)&xs[eg * 4 + 3][k];
#pragma unroll
    for (int dk = 0; dk < 4; ++dk) {
      const float4 w0 = *(const float4*)(w + (long)(k + dk) * HD + i0);
      const float4 w1 = *(const float4*)(w + (long)(k + dk) * HD + i0 + 4);
      const float a0 = GET4(xv0, dk), a1 = GET4(xv1, dk), a2 = GET4(xv2, dk), a3 = GET4(xv3, dk);
#pragma unroll
      for (int c = 0; c < 4; ++c) {
        const float wa = GET4(w0, c), wb = GET4(w1, c);
        acc[0][c] += a0 * wa; acc[0][c + 4] += a0 * wb;
        acc[1][c] += a1 * wa; acc[1][c + 4] += a1 * wb;
        acc[2][c] += a2 * wa; acc[2][c + 4] += a2 * wb;
        acc[3][c] += a3 * wa; acc[3][c + 4] += a3 * wb;
      }
    }
  }
  const float4 b0 = *(const float4*)(bias + i0);
  const float4 b1 = *(const float4*)(bias + i0 + 4);
#pragma unroll
  for (int a = 0; a < 4; ++a) {
    const long e = e0 + eg * 4 + a;
    if (e >= EDGES) continue;
    float o[8];
#pragma unroll
    for (int c = 0; c < 4; ++c) {
      o[c]     = silu_f(acc[a][c]     + GET4(b0, c));
      o[c + 4] = silu_f(acc[a][c + 4] + GET4(b1, c));
    }
    if (ADD) {
      const float4 ad0 = *(const float4*)(addsrc + e * HD + i0);
      const float4 ad1 = *(const float4*)(addsrc + e * HD + i0 + 4);
#pragma unroll
      for (int c = 0; c < 4; ++c) { o[c] += GET4(ad0, c); o[c + 4] += GET4(ad1, c); }
    }
    *(float4*)(out + e * HD + i0)     = make_float4(o[0], o[1], o[2], o[3]);
    *(float4*)(out + e * HD + i0 + 4) = make_float4(o[4], o[5], o[6], o[7]);
  }
}

// ---------------- fused residual: out = in + silu(silu(in@w1+b1)@w2+b2) ----------------

__global__ __launch_bounds__(256, 2) void k_res(const float* __restrict__ in,
    const float* __restrict__ w1, const float* __restrict__ b1,
    const float* __restrict__ w2, const float* __restrict__ b2,
    float* __restrict__ out) {
  __shared__ float xs[64][HD + 4];
  __shared__ float ts[64][HD + 4];
  const int tid = threadIdx.x;
  const long e0 = (long)blockIdx.x * 64;
  for (int idx = tid; idx < 64 * (HD / 4); idx += 256) {
    const int el = idx >> 5; const int k4 = (idx & 31) << 2;
    const long e = e0 + el;
    float4 v = make_float4(0.f, 0.f, 0.f, 0.f);
    if (e < EDGES) v = *(const float4*)(in + e * HD + k4);
    *(float4*)&xs[el][k4] = v;
  }
  __syncthreads();
  const int cg = tid & 15, eg = tid >> 4;
  const int i0 = cg * 8;
  {
    float acc[4][8] = {};
    for (int k = 0; k < HD; k += 4) {
      const float4 xv0 = *(const float4*)&xs[eg * 4 + 0][k];
      const float4 xv1 = *(const float4*)&xs[eg * 4 + 1][k];
      const float4 xv2 = *(const float4*)&xs[eg * 4 + 2][k];
      const float4 xv3 = *(const float4*)&xs[eg * 4 + 3][k];
#pragma unroll
      for (int dk = 0; dk < 4; ++dk) {
        const float4 w0 = *(const float4*)(w1 + (long)(k + dk) * HD + i0);
        const float4 w1v = *(const float4*)(w1 + (long)(k + dk) * HD + i0 + 4);
        const float a0 = GET4(xv0, dk), a1 = GET4(xv1, dk), a2 = GET4(xv2, dk), a3 = GET4(xv3, dk);
#pragma unroll
        for (int c = 0; c < 4; ++c) {
          const float wa = GET4(w0, c), wb = GET4(w1v, c);
          acc[0][c] += a0 * wa; acc[0][c + 4] += a0 * wb;
          acc[1][c] += a1 * wa; acc[1][c + 4] += a1 * wb;
          acc[2][c] += a2 * wa; acc[2][c + 4] += a2 * wb;
          acc[3][c] += a3 * wa; acc[3][c + 4] += a3 * wb;
        }
      }
    }
    const float4 c0 = *(const float4*)(b1 + i0);
    const float4 c1 = *(const float4*)(b1 + i0 + 4);
#pragma unroll
    for (int a = 0; a < 4; ++a) {
      float o[8];
#pragma unroll
      for (int c = 0; c < 4; ++c) {
        o[c]     = silu_f(acc[a][c]     + GET4(c0, c));
        o[c + 4] = silu_f(acc[a][c + 4] + GET4(c1, c));
      }
      *(float4*)&ts[eg * 4 + a][i0]     = make_float4(o[0], o[1], o[2], o[3]);
      *(float4*)&ts[eg * 4 + a][i0 + 4] = make_float4(o[4], o[5], o[6], o[7]);
    }
  }
  __syncthreads();
  {
    float acc[4][8] = {};
    for (int k = 0; k < HD; k += 4) {
      const float4 xv0 = *(const float4*)&ts[eg * 4 + 0][k];
      const float4 xv1 = *(const float4*)&ts[eg * 4 + 1][k];
      const float4 xv2 = *(const float4*)&ts[eg * 4 + 2][k];
      const float4 xv3 = *(const float4*)&ts[eg * 4 + 3][k];
#pragma unroll
      for (int dk = 0; dk < 4; ++dk) {
        const float4 w0 = *(const float4*)(w2 + (long)(k + dk) * HD + i0);
        const float4 w1v = *(const float4*)(w2 + (long)(k + dk) * HD + i0 + 4);
        const float a0 = GET4(xv0, dk), a1 = GET4(xv1, dk), a2 = GET4(xv2, dk), a3 = GET4(xv3, dk);
#pragma unroll
        for (int c = 0; c < 4; ++c) {
          const float wa = GET4(w0, c), wb = GET4(w1v, c);
          acc[0][c] += a0 * wa; acc[0][c + 4] += a0 * wb;
          acc[1][c] += a1 * wa; acc[1][c + 4] += a1 * wb;
          acc[2][c] += a2 * wa; acc[2][c + 4] += a2 * wb;
          acc[3][c] += a3 * wa; acc[3][c + 4] += a3 * wb;
        }
      }
    }
    const float4 c0 = *(const float4*)(b2 + i0);
    const float4 c1 = *(const float4*)(b2 + i0 + 4);
#pragma unroll
    for (int a = 0; a < 4; ++a) {
      const long e = e0 + eg * 4 + a;
      if (e >= EDGES) continue;
      float o[8];
#pragma unroll
      for (int c = 0; c < 4; ++c) {
        o[c]     = silu_f(acc[a][c]     + GET4(c0, c)) + xs[eg * 4 + a][i0 + c];
        o[c + 4] = silu_f(acc[a][c + 4] + GET4(c1, c)) + xs[eg * 4 + a][i0 + 4 + c];
      }
      *(float4*)(out + e * HD + i0)     = make_float4(o[0], o[1], o[2], o[3]);
      *(float4*)(out + e * HD + i0 + 4) = make_float4(o[4], o[5], o[6], o[7]);
    }
  }
}

// ---------------- launch ----------------

extern "C" void kernel_launch(void* const* d_in, const int* in_sizes, int n_in,
                              void* d_out, int out_size, void* d_ws, size_t ws_size,
                              hipStream_t stream) {
  const float* x         = (const float*)d_in[0];
  const float* rbf       = (const float*)d_in[1];
  const float* sbf       = (const float*)d_in[2];
  const int*   idx_kj    = (const int*)d_in[3];
  const int*   idx_ji    = (const int*)d_in[4];
  const float* lin_rbf_w = (const float*)d_in[5];
  const float* lin_sbf_w = (const float*)d_in[6];
  const float* lin_kj_w  = (const float*)d_in[7];
  const float* lin_kj_b  = (const float*)d_in[8];
  const float* lin_ji_w  = (const float*)d_in[9];
  const float* lin_ji_b  = (const float*)d_in[10];
  const float* Wtri      = (const float*)d_in[11];
  const float* rb_w1 = (const float*)d_in[12];
  const float* rb_b1 = (const float*)d_in[13];
  const float* rb_w2 = (const float*)d_in[14];
  const float* rb_b2 = (const float*)d_in[15];
  const float* lin_w = (const float*)d_in[16];
  const float* lin_b = (const float*)d_in[17];
  const float* ra1_w1 = (const float*)d_in[18];
  const float* ra1_b1 = (const float*)d_in[19];
  const float* ra1_w2 = (const float*)d_in[20];
  const float* ra1_b2 = (const float*)d_in[21];
  const float* ra2_w1 = (const float*)d_in[22];
  const float* ra2_b1 = (const float*)d_in[23];
  const float* ra2_w2 = (const float*)d_in[24];
  const float* ra2_b2 = (const float*)d_in[25];
  const float* lin_out_w = (const float*)d_in[26];
  const float* lin_out_b = (const float*)d_in[27];
  float* outp = (float*)d_out;

  const size_t EH = (size_t)EDGES * HD;
  float* buf0 = (float*)d_ws;                    // x_ji
  float* buf1 = buf0 + EH;                       // x_kj
  float* buf2 = buf1 + EH;                       // h
  float* sbfp = buf2 + EH;                       // sbf_h sorted [T,8]
  float* wt   = sbfp + (size_t)TRIP * NBIL;      // [1024,128]
  float* fend = wt + (size_t)NBIL * HD * HD;
  int* offs   = (int*)fend;                      // E+1 (alloc E+4 for alignment)
  int* cursor = offs + (EDGES + 4);
  int* gkj    = cursor + EDGES;
  int* tpos   = gkj + TRIP;
  int* blks   = tpos + TRIP;
  int* iend   = blks + 256;
  const size_t base_bytes = (size_t)((char*)iend - (char*)d_ws);
  const size_t moff = (base_bytes + 255) & ~(size_t)255;
  float* Mbuf = (float*)((char*)d_ws + moff);
  long ce = 0;
  if ((long)ws_size > (long)moff) {
    ce = ((long)ws_size - (long)moff) / (1024 * 4);
    ce &= ~63L;
    if (ce > 250048) ce = 250048;     // one chunk covers all edges (rounded to 64)
  }
  const bool split = (ce >= 8192);

  hipMemsetAsync(cursor, 0, EDGES * sizeof(int), stream);
  const int TB  = (TRIP + 255) / 256;
  const int SCB = (EDGES + 1023) / 1024;
  k_hist<<<TB, 256, 0, stream>>>(idx_ji, cursor);
  k_scan1<<<SCB, 256, 0, stream>>>(cursor, blks);
  k_scan2<<<1, 256, 0, stream>>>(blks, SCB);
  k_scan3<<<SCB, 256, 0, stream>>>(cursor, blks, offs);
  k_scatter<<<TB, 256, 0, stream>>>(idx_ji, idx_kj, cursor, gkj, tpos);
  k_wt<<<(NBIL * HD * HD + 255) / 256, 256, 0, stream>>>(Wtri, wt);
  k_sbfh<<<TB, 256, 0, stream>>>(sbf, lin_sbf_w, tpos, sbfp);
  k_edge<<<(EDGES + 31) / 32, 256, 0, stream>>>(x, rbf, lin_rbf_w,
      lin_ji_w, lin_ji_b, lin_kj_w, lin_kj_b, buf0, buf1);

  if (split) {
    for (long c0 = 0; c0 < EDGES; c0 += ce) {
      const int ecount = (int)((EDGES - c0 < ce) ? (EDGES - c0) : ce);
      k_mA<<<(ecount + 3) / 4, 256, 0, stream>>>(buf1, sbfp, gkj, offs, Mbuf, (int)c0, ecount);
      k_mB<<<(ecount + 63) / 64, 256, 0, stream>>>(Mbuf, wt, buf0, buf2, (int)c0, ecount);
    }
  } else {
    k_m<<<EDGES / 16, 256, 0, stream>>>(buf1, sbfp, gkj, offs, wt, buf0, buf2);
  }

  const int GB = (EDGES + 63) / 64;
  k_res<<<GB, 256, 0, stream>>>(buf2, rb_w1, rb_b1, rb_w2, rb_b2, buf0);       // h1
  k_gemm<true ><<<GB, 256, 0, stream>>>(buf0, lin_w, lin_b, x, buf1);          // h2 = silu(..)+x
  k_res<<<GB, 256, 0, stream>>>(buf1, ra1_w1, ra1_b1, ra1_w2, ra1_b2, buf2);   // h3
  k_res<<<GB, 256, 0, stream>>>(buf2, ra2_w1, ra2_b1, ra2_w2, ra2_b2, buf0);   // h4
  k_gemm<false><<<GB, 256, 0, stream>>>(buf0, lin_out_w, lin_out_b, nullptr, outp);
}

// Round 4
// 3978.485 us; speedup vs baseline: 1.5886x; 1.0564x over previous
//
#include <hip/hip_runtime.h>

// Problem constants (fixed by the reference)
#define EDGES 250000
#define TRIP  1500000
#define HD    128
#define NBIL  8
#define NSR   42
#define NRAD  6

__device__ __forceinline__ float silu_f(float v) {
  return v / (1.0f + __expf(-v));
}

#define GET4(v,i) ((i)==0?(v).x:((i)==1?(v).y:((i)==2?(v).z:(v).w)))

// ---------------- counting sort of triplets by idx_ji ----------------

__global__ void k_hist(const int* __restrict__ idxji, int* __restrict__ hist) {
  const int t = blockIdx.x * 256 + threadIdx.x;
  if (t < TRIP) atomicAdd(&hist[idxji[t]], 1);
}

__global__ __launch_bounds__(256) void k_scan1(const int* __restrict__ hist, int* __restrict__ blks) {
  __shared__ int sd[256];
  const int tid = threadIdx.x;
  const long base = (long)blockIdx.x * 1024 + tid * 4;
  int s = 0;
#pragma unroll
  for (int u = 0; u < 4; ++u) { const long i = base + u; if (i < EDGES) s += hist[i]; }
  sd[tid] = s; __syncthreads();
  for (int off = 128; off > 0; off >>= 1) { if (tid < off) sd[tid] += sd[tid + off]; __syncthreads(); }
  if (tid == 0) blks[blockIdx.x] = sd[0];
}

__global__ __launch_bounds__(256) void k_scan2(int* __restrict__ blks, int n) {
  __shared__ int sd[256];
  const int tid = threadIdx.x;
  const int v = (tid < n) ? blks[tid] : 0;
  sd[tid] = v; __syncthreads();
  for (int off = 1; off < 256; off <<= 1) {
    const int t = (tid >= off) ? sd[tid - off] : 0;
    __syncthreads();
    sd[tid] += t;
    __syncthreads();
  }
  if (tid < n) blks[tid] = sd[tid] - v;   // exclusive
}

// reads hist from `cursor`, writes exclusive scan to offs[] AND back into cursor[]
__global__ __launch_bounds__(256) void k_scan3(int* __restrict__ cursor, const int* __restrict__ blks,
                                               int* __restrict__ offs) {
  __shared__ int sd[256];
  const int tid = threadIdx.x;
  const long base = (long)blockIdx.x * 1024 + tid * 4;
  int v[4]; int s = 0;
#pragma unroll
  for (int u = 0; u < 4; ++u) { const long i = base + u; v[u] = (i < EDGES) ? cursor[i] : 0; s += v[u]; }
  sd[tid] = s; __syncthreads();
  for (int off = 1; off < 256; off <<= 1) {
    const int tv = (tid >= off) ? sd[tid - off] : 0;
    __syncthreads();
    sd[tid] += tv;
    __syncthreads();
  }
  int run = blks[blockIdx.x] + sd[tid] - s;
#pragma unroll
  for (int u = 0; u < 4; ++u) {
    const long i = base + u;
    if (i < EDGES) { offs[i] = run; cursor[i] = run; }
    run += v[u];
  }
  if (blockIdx.x == 0 && tid == 0) offs[EDGES] = TRIP;
}

__global__ void k_scatter(const int* __restrict__ idxji, const int* __restrict__ idxkj,
                          int* __restrict__ cursor, int* __restrict__ gkj, int* __restrict__ tpos) {
  const int t = blockIdx.x * 256 + threadIdx.x;
  if (t < TRIP) {
    const int e = idxji[t];
    const int pos = atomicAdd(&cursor[e], 1);
    gkj[pos] = idxkj[t];
    tpos[t] = pos;
  }
}

// ---------------- W transpose: wt[(j*128+l)*128 + i] = W[i][j][l] ----------------

__global__ void k_wt(const float* __restrict__ W, float* __restrict__ wt) {
  const int idx = blockIdx.x * 256 + threadIdx.x;
  if (idx < NBIL * HD * HD) {
    const int i = idx & (HD - 1);
    const int k = idx >> 7;          // j*128 + l
    const int j = k >> 7;
    const int l = k & (HD - 1);
    wt[idx] = W[((long)i * NBIL + j) * HD + l];
  }
}

// ---------------- sbf_h = sbf @ lin_sbf_w, written in sorted (pos) order ----------------

__global__ __launch_bounds__(256) void k_sbfh(const float* __restrict__ sbf,
    const float* __restrict__ sw, const int* __restrict__ tpos, float* __restrict__ outp) {
  __shared__ float ss[256 * NSR];
  __shared__ float wls[NSR * NBIL];
  const int tid = threadIdx.x;
  const long t0 = (long)blockIdx.x * 256;
  const long gbase = t0 * NSR;
  for (int idx = tid; idx < 256 * NSR; idx += 256) {
    const long gi = gbase + idx;
    ss[idx] = (gi < (long)TRIP * NSR) ? sbf[gi] : 0.f;
  }
  for (int idx = tid; idx < NSR * NBIL; idx += 256) wls[idx] = sw[idx];
  __syncthreads();
  const long t = t0 + tid;
  if (t < TRIP) {
    float o[NBIL] = {};
    for (int r = 0; r < NSR; ++r) {
      const float sv = ss[tid * NSR + r];
#pragma unroll
      for (int j = 0; j < NBIL; ++j) o[j] += sv * wls[r * NBIL + j];
    }
    const long p = tpos[t];
    *(float4*)(outp + p * 8) = make_float4(o[0], o[1], o[2], o[3]);
    *(float4*)(outp + p * 8 + 4) = make_float4(o[4], o[5], o[6], o[7]);
  }
}

// ---------------- edge kernel: x_ji, x_kj (dual GEMM + silu + rbf_h) ----------------

__global__ __launch_bounds__(256, 4) void k_edge(const float* __restrict__ x,
    const float* __restrict__ rbf, const float* __restrict__ rbfw,
    const float* __restrict__ wji, const float* __restrict__ bji,
    const float* __restrict__ wkj, const float* __restrict__ bkj,
    float* __restrict__ xji, float* __restrict__ xkj) {
  __shared__ float xs[32][HD + 4];
  __shared__ float rbfs[32][NRAD];
  __shared__ float rws[NRAD][HD];
  const int tid = threadIdx.x;
  const long e0 = (long)blockIdx.x * 32;
  for (int idx = tid; idx < 32 * (HD / 4); idx += 256) {
    const int el = idx >> 5; const int k4 = (idx & 31) << 2;
    const long e = e0 + el;
    float4 v = make_float4(0.f, 0.f, 0.f, 0.f);
    if (e < EDGES) v = *(const float4*)(x + e * HD + k4);
    *(float4*)&xs[el][k4] = v;
  }
  for (int idx = tid; idx < 32 * NRAD; idx += 256) {
    const int el = idx / NRAD, r = idx % NRAD;
    const long e = e0 + el;
    rbfs[el][r] = (e < EDGES) ? rbf[e * NRAD + r] : 0.f;
  }
  for (int idx = tid; idx < NRAD * HD; idx += 256) rws[idx / HD][idx % HD] = rbfw[idx];
  __syncthreads();
  const int cg = tid & 15, eg = tid >> 4;   // 16 col-groups x 16 edge-groups (2 edges each)
  const int i0 = cg * 8;
  float aj[2][8] = {}, ak[2][8] = {};
  for (int k = 0; k < HD; k += 4) {
    const float4 xv0 = *(const float4*)&xs[eg * 2 + 0][k];
    const float4 xv1 = *(const float4*)&xs[eg * 2 + 1][k];
#pragma unroll
    for (int dk = 0; dk < 4; ++dk) {
      const float4 j0 = *(const float4*)(wji + (long)(k + dk) * HD + i0);
      const float4 j1 = *(const float4*)(wji + (long)(k + dk) * HD + i0 + 4);
      const float4 q0 = *(const float4*)(wkj + (long)(k + dk) * HD + i0);
      const float4 q1 = *(const float4*)(wkj + (long)(k + dk) * HD + i0 + 4);
      const float a0 = GET4(xv0, dk), a1 = GET4(xv1, dk);
#pragma unroll
      for (int c = 0; c < 4; ++c) {
        const float wja = GET4(j0, c), wjb = GET4(j1, c);
        const float wka = GET4(q0, c), wkb = GET4(q1, c);
        aj[0][c] += a0 * wja; aj[0][c + 4] += a0 * wjb;
        aj[1][c] += a1 * wja; aj[1][c + 4] += a1 * wjb;
        ak[0][c] += a0 * wka; ak[0][c + 4] += a0 * wkb;
        ak[1][c] += a1 * wka; ak[1][c + 4] += a1 * wkb;
      }
    }
  }
  const float4 bj0 = *(const float4*)(bji + i0), bj1 = *(const float4*)(bji + i0 + 4);
  const float4 bk0 = *(const float4*)(bkj + i0), bk1 = *(const float4*)(bkj + i0 + 4);
#pragma unroll
  for (int a = 0; a < 2; ++a) {
    const int el = eg * 2 + a;
    const long e = e0 + el;
    if (e >= EDGES) continue;
    float rh[8];
#pragma unroll
    for (int c = 0; c < 8; ++c) rh[c] = 0.f;
#pragma unroll
    for (int r = 0; r < NRAD; ++r) {
      const float rv = rbfs[el][r];
#pragma unroll
      for (int c = 0; c < 8; ++c) rh[c] += rv * rws[r][i0 + c];
    }
    float oj[8], ok[8];
#pragma unroll
    for (int c = 0; c < 4; ++c) {
      oj[c]     = silu_f(aj[a][c]     + GET4(bj0, c));
      oj[c + 4] = silu_f(aj[a][c + 4] + GET4(bj1, c));
      ok[c]     = silu_f(ak[a][c]     + GET4(bk0, c)) * rh[c];
      ok[c + 4] = silu_f(ak[a][c + 4] + GET4(bk1, c)) * rh[c + 4];
    }
    *(float4*)(xji + e * HD + i0)     = make_float4(oj[0], oj[1], oj[2], oj[3]);
    *(float4*)(xji + e * HD + i0 + 4) = make_float4(oj[4], oj[5], oj[6], oj[7]);
    *(float4*)(xkj + e * HD + i0)     = make_float4(ok[0], ok[1], ok[2], ok[3]);
    *(float4*)(xkj + e * HD + i0 + 4) = make_float4(ok[4], ok[5], ok[6], ok[7]);
  }
}

// ---------------- outer-product accumulation ----------------

#define FMA16(sA, sB, xv) do { \
  m[0]  += (sA).x * (xv).x;  m[1]  += (sA).x * (xv).y; \
  m[2]  += (sA).y * (xv).x;  m[3]  += (sA).y * (xv).y; \
  m[4]  += (sA).z * (xv).x;  m[5]  += (sA).z * (xv).y; \
  m[6]  += (sA).w * (xv).x;  m[7]  += (sA).w * (xv).y; \
  m[8]  += (sB).x * (xv).x;  m[9]  += (sB).x * (xv).y; \
  m[10] += (sB).y * (xv).x;  m[11] += (sB).y * (xv).y; \
  m[12] += (sB).z * (xv).x;  m[13] += (sB).z * (xv).y; \
  m[14] += (sB).w * (xv).x;  m[15] += (sB).w * (xv).y; } while (0)

#define ACCUM_SEGMENT(t0, t1) \
    int t = (t0); \
    for (; t + 4 <= (t1); t += 4) { \
      const int g0 = gkj[t], g1 = gkj[t + 1], g2 = gkj[t + 2], g3 = gkj[t + 3]; \
      const float2 x0 = *(const float2*)(xkj + (long)g0 * HD + l2); \
      const float2 x1 = *(const float2*)(xkj + (long)g1 * HD + l2); \
      const float2 x2 = *(const float2*)(xkj + (long)g2 * HD + l2); \
      const float2 x3 = *(const float2*)(xkj + (long)g3 * HD + l2); \
      const float4 sa0 = *(const float4*)(sbfp + (long)t * 8); \
      const float4 sb0 = *(const float4*)(sbfp + (long)t * 8 + 4); \
      const float4 sa1 = *(const float4*)(sbfp + (long)(t + 1) * 8); \
      const float4 sb1 = *(const float4*)(sbfp + (long)(t + 1) * 8 + 4); \
      const float4 sa2 = *(const float4*)(sbfp + (long)(t + 2) * 8); \
      const float4 sb2 = *(const float4*)(sbfp + (long)(t + 2) * 8 + 4); \
      const float4 sa3 = *(const float4*)(sbfp + (long)(t + 3) * 8); \
      const float4 sb3 = *(const float4*)(sbfp + (long)(t + 3) * 8 + 4); \
      FMA16(sa0, sb0, x0); \
      FMA16(sa1, sb1, x1); \
      FMA16(sa2, sb2, x2); \
      FMA16(sa3, sb3, x3); \
    } \
    for (; t < (t1); ++t) { \
      const int g = gkj[t]; \
      const float2 xv = *(const float2*)(xkj + (long)g * HD + l2); \
      const float4 sa = *(const float4*)(sbfp + (long)t * 8); \
      const float4 sb = *(const float4*)(sbfp + (long)t * 8 + 4); \
      FMA16(sa, sb, xv); \
    }

// k_mA: M[er][j*128+l] = sum over segment of sbf_h[t][j]*xk[t][l]; 1 wave per edge,
// no LDS -> high occupancy, gather latency hidden by ~20 waves/CU.
__global__ __launch_bounds__(256, 4) void k_mA(const float* __restrict__ xkj,
    const float* __restrict__ sbfp, const int* __restrict__ gkj,
    const int* __restrict__ offs, float* __restrict__ M, int e0chunk, int ecount) {
  const int tid = threadIdx.x;
  const int lane = tid & 63;
  const int wv = tid >> 6;
  const int er = blockIdx.x * 4 + wv;
  if (er >= ecount) return;
  const long e = (long)e0chunk + er;
  const int l2 = lane * 2;
  float m[16];
#pragma unroll
  for (int q = 0; q < 16; ++q) m[q] = 0.f;
  const int t0 = offs[e], t1 = offs[e + 1];
  { ACCUM_SEGMENT(t0, t1) }
#pragma unroll
  for (int j = 0; j < 8; ++j)
    *(float2*)(M + (long)er * 1024 + j * 128 + l2) = make_float2(m[2 * j], m[2 * j + 1]);
}

// k_mB v2: h = x_ji + M @ wt   ([ecount,1024] @ [1024,128])
// 128-edge x 128-col block tile, KC=32 K-chunks, M-tile AND wt-tile staged in LDS,
// 8x8 register tile per thread. Row mapping row = eg + 16*ri makes M-tile ds_read_b128
// conflict-free (banks 4*eg apart). k-summation order identical to v1 (bit-identical out).
#define KC 32

__global__ __launch_bounds__(256, 4) void k_mB(const float* __restrict__ M,
    const float* __restrict__ wt, const float* __restrict__ xji,
    float* __restrict__ hout, int e0chunk, int ecount) {
  __shared__ float ms[128][KC + 4];     // 18432 B, stride 36 floats (144 B, 16B-aligned)
  __shared__ float ws[KC][HD + 4];      // 16896 B, stride 132 floats
  const int tid = threadIdx.x;
  const int rbase = blockIdx.x * 128;
  const int cg = tid & 15, eg = tid >> 4;   // 16 col-groups x 16 row-groups
  const int i0 = cg * 8;
  // staging coords
  const int mc4 = (tid & 7) << 2;       // 0..28
  const int mrow = tid >> 3;            // 0..31
  const int wc4 = (tid & 31) << 2;      // 0..124
  const int wkr = tid >> 5;             // 0..7
  float acc[8][8] = {};
  for (int kc = 0; kc < 1024; kc += KC) {
    __syncthreads();
    // stage M tile: 128 rows x 32 k (lanes sweep k within a row -> coalesced 128B/row)
#pragma unroll
    for (int rr = 0; rr < 4; ++rr) {
      const int r = mrow + rr * 32;
      const int grow = rbase + r;
      float4 v = make_float4(0.f, 0.f, 0.f, 0.f);
      if (grow < ecount) v = *(const float4*)(M + (long)grow * 1024 + kc + mc4);
      *(float4*)&ms[r][mc4] = v;
    }
    // stage wt tile: 32 k x 128 cols (32 lanes sweep one k-row -> coalesced 512B/row)
#pragma unroll
    for (int kk = 0; kk < 4; ++kk) {
      const int k = wkr * 4 + kk;
      *(float4*)&ws[k][wc4] = *(const float4*)(wt + (long)(kc + k) * HD + wc4);
    }
    __syncthreads();
    for (int k4 = 0; k4 < KC; k4 += 4) {
      float4 w[8];
#pragma unroll
      for (int dk = 0; dk < 4; ++dk) {
        w[2 * dk]     = *(const float4*)&ws[k4 + dk][i0];
        w[2 * dk + 1] = *(const float4*)&ws[k4 + dk][i0 + 4];
      }
#pragma unroll
      for (int ri = 0; ri < 8; ++ri) {
        const float4 mv = *(const float4*)&ms[eg + 16 * ri][k4];
#pragma unroll
        for (int dk = 0; dk < 4; ++dk) {
          const float a = GET4(mv, dk);
          const float4 wa = w[2 * dk], wb = w[2 * dk + 1];
          acc[ri][0] += a * wa.x; acc[ri][1] += a * wa.y;
          acc[ri][2] += a * wa.z; acc[ri][3] += a * wa.w;
          acc[ri][4] += a * wb.x; acc[ri][5] += a * wb.y;
          acc[ri][6] += a * wb.z; acc[ri][7] += a * wb.w;
        }
      }
    }
  }
#pragma unroll
  for (int ri = 0; ri < 8; ++ri) {
    const int row = rbase + eg + 16 * ri;
    if (row >= ecount) continue;
    const long e = (long)e0chunk + row;
    const float4 xa = *(const float4*)(xji + e * HD + i0);
    const float4 xb = *(const float4*)(xji + e * HD + i0 + 4);
    *(float4*)(hout + e * HD + i0)     = make_float4(acc[ri][0] + xa.x, acc[ri][1] + xa.y,
                                                     acc[ri][2] + xa.z, acc[ri][3] + xa.w);
    *(float4*)(hout + e * HD + i0 + 4) = make_float4(acc[ri][4] + xb.x, acc[ri][5] + xb.y,
                                                     acc[ri][6] + xb.z, acc[ri][7] + xb.w);
  }
}

// ---------------- fallback fused M-kernel (used only if d_ws too small) ----------------

__global__ __launch_bounds__(256, 2) void k_m(const float* __restrict__ xkj,
    const float* __restrict__ sbfp, const int* __restrict__ gkj,
    const int* __restrict__ offs, const float* __restrict__ wt,
    const float* __restrict__ xji, float* __restrict__ hout) {
  __shared__ float Mt[16][1024];
  const int tid = threadIdx.x;
  const int lane = tid & 63;
  const int wv = tid >> 6;
  const long e0 = (long)blockIdx.x * 16;
  const int l2 = lane * 2;
#pragma unroll 1
  for (int es = 0; es < 4; ++es) {
    const int el = wv * 4 + es;
    const long e = e0 + el;
    float m[16];
#pragma unroll
    for (int q = 0; q < 16; ++q) m[q] = 0.f;
    const int t0 = offs[e], t1 = offs[e + 1];
    { ACCUM_SEGMENT(t0, t1) }
#pragma unroll
    for (int j = 0; j < 8; ++j)
      *(float2*)&Mt[el][j * 128 + l2] = make_float2(m[2 * j], m[2 * j + 1]);
  }
  __syncthreads();
  const int cg = tid & 15, er = tid >> 4;
  const int i0 = cg * 8;
  float acc[8] = {};
  for (int kk = 0; kk < 1024; kk += 4) {
    const float4 mv = *(const float4*)&Mt[er][kk];
#pragma unroll
    for (int dk = 0; dk < 4; ++dk) {
      const float4 w0 = *(const float4*)(wt + (long)(kk + dk) * HD + i0);
      const float4 w1 = *(const float4*)(wt + (long)(kk + dk) * HD + i0 + 4);
      const float md = GET4(mv, dk);
      acc[0] += md * w0.x; acc[1] += md * w0.y; acc[2] += md * w0.z; acc[3] += md * w0.w;
      acc[4] += md * w1.x; acc[5] += md * w1.y; acc[6] += md * w1.z; acc[7] += md * w1.w;
    }
  }
  const long e = e0 + er;
  const float4 xa = *(const float4*)(xji + e * HD + i0);
  const float4 xb = *(const float4*)(xji + e * HD + i0 + 4);
  *(float4*)(hout + e * HD + i0)     = make_float4(acc[0] + xa.x, acc[1] + xa.y, acc[2] + xa.z, acc[3] + xa.w);
  *(float4*)(hout + e * HD + i0 + 4) = make_float4(acc[4] + xb.x, acc[5] + xb.y, acc[6] + xb.z, acc[7] + xb.w);
}

// ---------------- generic [E,128]@[128,128] + bias + silu (+add) ----------------

template<bool ADD>
__global__ __launch_bounds__(256, 4) void k_gemm(const float* __restrict__ in,
    const float* __restrict__ w, const float* __restrict__ bias,
    const float* __restrict__ addsrc, float* __restrict__ out) {
  __shared__ float xs[64][HD + 4];
  const int tid = threadIdx.x;
  const long e0 = (long)blockIdx.x * 64;
  for (int idx = tid; idx < 64 * (HD / 4); idx += 256) {
    const int el = idx >> 5; const int k4 = (idx & 31) << 2;
    const long e = e0 + el;
    float4 v = make_float4(0.f, 0.f, 0.f, 0.f);
    if (e < EDGES) v = *(const float4*)(in + e * HD + k4);
    *(float4*)&xs[el][k4] = v;
  }
  __syncthreads();
  const int cg = tid & 15, eg = tid >> 4;
  const int i0 = cg * 8;
  float acc[4][8] = {};
  for (int k = 0; k < HD; k += 4) {
    const float4 xv0 = *(const float4*)&xs[eg * 4 + 0][k];
    const float4 xv1 = *(const float4*)&xs[eg * 4 + 1][k];
    const float4 xv2 = *(const float4*)&xs[eg * 4 + 2][k];
    const float4 xv3 = *(const float4*)&xs[eg * 4 + 3][k];
#pragma unroll
    for (int dk = 0; dk < 4; ++dk) {
      const float4 w0 = *(const float4*)(w + (long)(k + dk) * HD + i0);
      const float4 w1 = *(const float4*)(w + (long)(k + dk) * HD + i0 + 4);
      const float a0 = GET4(xv0, dk), a1 = GET4(xv1, dk), a2 = GET4(xv2, dk), a3 = GET4(xv3, dk);
#pragma unroll
      for (int c = 0; c < 4; ++c) {
        const float wa = GET4(w0, c), wb = GET4(w1, c);
        acc[0][c] += a0 * wa; acc[0][c + 4] += a0 * wb;
        acc[1][c] += a1 * wa; acc[1][c + 4] += a1 * wb;
        acc[2][c] += a2 * wa; acc[2][c + 4] += a2 * wb;
        acc[3][c] += a3 * wa; acc[3][c + 4] += a3 * wb;
      }
    }
  }
  const float4 b0 = *(const float4*)(bias + i0);
  const float4 b1 = *(const float4*)(bias + i0 + 4);
#pragma unroll
  for (int a = 0; a < 4; ++a) {
    const long e = e0 + eg * 4 + a;
    if (e >= EDGES) continue;
    float o[8];
#pragma unroll
    for (int c = 0; c < 4; ++c) {
      o[c]     = silu_f(acc[a][c]     + GET4(b0, c));
      o[c + 4] = silu_f(acc[a][c + 4] + GET4(b1, c));
    }
    if (ADD) {
      const float4 ad0 = *(const float4*)(addsrc + e * HD + i0);
      const float4 ad1 = *(const float4*)(addsrc + e * HD + i0 + 4);
#pragma unroll
      for (int c = 0; c < 4; ++c) { o[c] += GET4(ad0, c); o[c + 4] += GET4(ad1, c); }
    }
    *(float4*)(out + e * HD + i0)     = make_float4(o[0], o[1], o[2], o[3]);
    *(float4*)(out + e * HD + i0 + 4) = make_float4(o[4], o[5], o[6], o[7]);
  }
}

// ---------------- fused residual: out = in + silu(silu(in@w1+b1)@w2+b2) ----------------

__global__ __launch_bounds__(256, 2) void k_res(const float* __restrict__ in,
    const float* __restrict__ w1, const float* __restrict__ b1,
    const float* __restrict__ w2, const float* __restrict__ b2,
    float* __restrict__ out) {
  __shared__ float xs[64][HD + 4];
  __shared__ float ts[64][HD + 4];
  const int tid = threadIdx.x;
  const long e0 = (long)blockIdx.x * 64;
  for (int idx = tid; idx < 64 * (HD / 4); idx += 256) {
    const int el = idx >> 5; const int k4 = (idx & 31) << 2;
    const long e = e0 + el;
    float4 v = make_float4(0.f, 0.f, 0.f, 0.f);
    if (e < EDGES) v = *(const float4*)(in + e * HD + k4);
    *(float4*)&xs[el][k4] = v;
  }
  __syncthreads();
  const int cg = tid & 15, eg = tid >> 4;
  const int i0 = cg * 8;
  {
    float acc[4][8] = {};
    for (int k = 0; k < HD; k += 4) {
      const float4 xv0 = *(const float4*)&xs[eg * 4 + 0][k];
      const float4 xv1 = *(const float4*)&xs[eg * 4 + 1][k];
      const float4 xv2 = *(const float4*)&xs[eg * 4 + 2][k];
      const float4 xv3 = *(const float4*)&xs[eg * 4 + 3][k];
#pragma unroll
      for (int dk = 0; dk < 4; ++dk) {
        const float4 w0 = *(const float4*)(w1 + (long)(k + dk) * HD + i0);
        const float4 w1v = *(const float4*)(w1 + (long)(k + dk) * HD + i0 + 4);
        const float a0 = GET4(xv0, dk), a1 = GET4(xv1, dk), a2 = GET4(xv2, dk), a3 = GET4(xv3, dk);
#pragma unroll
        for (int c = 0; c < 4; ++c) {
          const float wa = GET4(w0, c), wb = GET4(w1v, c);
          acc[0][c] += a0 * wa; acc[0][c + 4] += a0 * wb;
          acc[1][c] += a1 * wa; acc[1][c + 4] += a1 * wb;
          acc[2][c] += a2 * wa; acc[2][c + 4] += a2 * wb;
          acc[3][c] += a3 * wa; acc[3][c + 4] += a3 * wb;
        }
      }
    }
    const float4 c0 = *(const float4*)(b1 + i0);
    const float4 c1 = *(const float4*)(b1 + i0 + 4);
#pragma unroll
    for (int a = 0; a < 4; ++a) {
      float o[8];
#pragma unroll
      for (int c = 0; c < 4; ++c) {
        o[c]     = silu_f(acc[a][c]     + GET4(c0, c));
        o[c + 4] = silu_f(acc[a][c + 4] + GET4(c1, c));
      }
      *(float4*)&ts[eg * 4 + a][i0]     = make_float4(o[0], o[1], o[2], o[3]);
      *(float4*)&ts[eg * 4 + a][i0 + 4] = make_float4(o[4], o[5], o[6], o[7]);
    }
  }
  __syncthreads();
  {
    float acc[4][8] = {};
    for (int k = 0; k < HD; k += 4) {
      const float4 xv0 = *(const float4*)&ts[eg * 4 + 0][k];
      const float4 xv1 = *(const float4*)&ts[eg * 4 + 1][k];
      const float4 xv2 = *(const float4*)&ts[eg * 4 + 2][k];
      const float4 xv3 = *(const float4*)&ts[eg * 4 + 3][k];
#pragma unroll
      for (int dk = 0; dk < 4; ++dk) {
        const float4 w0 = *(const float4*)(w2 + (long)(k + dk) * HD + i0);
        const float4 w1v = *(const float4*)(w2 + (long)(k + dk) * HD + i0 + 4);
        const float a0 = GET4(xv0, dk), a1 = GET4(xv1, dk), a2 = GET4(xv2, dk), a3 = GET4(xv3, dk);
#pragma unroll
        for (int c = 0; c < 4; ++c) {
          const float wa = GET4(w0, c), wb = GET4(w1v, c);
          acc[0][c] += a0 * wa; acc[0][c + 4] += a0 * wb;
          acc[1][c] += a1 * wa; acc[1][c + 4] += a1 * wb;
          acc[2][c] += a2 * wa; acc[2][c + 4] += a2 * wb;
          acc[3][c] += a3 * wa; acc[3][c + 4] += a3 * wb;
        }
      }
    }
    const float4 c0 = *(const float4*)(b2 + i0);
    const float4 c1 = *(const float4*)(b2 + i0 + 4);
#pragma unroll
    for (int a = 0; a < 4; ++a) {
      const long e = e0 + eg * 4 + a;
      if (e >= EDGES) continue;
      float o[8];
#pragma unroll
      for (int c = 0; c < 4; ++c) {
        o[c]     = silu_f(acc[a][c]     + GET4(c0, c)) + xs[eg * 4 + a][i0 + c];
        o[c + 4] = silu_f(acc[a][c + 4] + GET4(c1, c)) + xs[eg * 4 + a][i0 + 4 + c];
      }
      *(float4*)(out + e * HD + i0)     = make_float4(o[0], o[1], o[2], o[3]);
      *(float4*)(out + e * HD + i0 + 4) = make_float4(o[4], o[5], o[6], o[7]);
    }
  }
}

// ---------------- launch ----------------

extern "C" void kernel_launch(void* const* d_in, const int* in_sizes, int n_in,
                              void* d_out, int out_size, void* d_ws, size_t ws_size,
                              hipStream_t stream) {
  const float* x         = (const float*)d_in[0];
  const float* rbf       = (const float*)d_in[1];
  const float* sbf       = (const float*)d_in[2];
  const int*   idx_kj    = (const int*)d_in[3];
  const int*   idx_ji    = (const int*)d_in[4];
  const float* lin_rbf_w = (const float*)d_in[5];
  const float* lin_sbf_w = (const float*)d_in[6];
  const float* lin_kj_w  = (const float*)d_in[7];
  const float* lin_kj_b  = (const float*)d_in[8];
  const float* lin_ji_w  = (const float*)d_in[9];
  const float* lin_ji_b  = (const float*)d_in[10];
  const float* Wtri      = (const float*)d_in[11];
  const float* rb_w1 = (const float*)d_in[12];
  const float* rb_b1 = (const float*)d_in[13];
  const float* rb_w2 = (const float*)d_in[14];
  const float* rb_b2 = (const float*)d_in[15];
  const float* lin_w = (const float*)d_in[16];
  const float* lin_b = (const float*)d_in[17];
  const float* ra1_w1 = (const float*)d_in[18];
  const float* ra1_b1 = (const float*)d_in[19];
  const float* ra1_w2 = (const float*)d_in[20];
  const float* ra1_b2 = (const float*)d_in[21];
  const float* ra2_w1 = (const float*)d_in[22];
  const float* ra2_b1 = (const float*)d_in[23];
  const float* ra2_w2 = (const float*)d_in[24];
  const float* ra2_b2 = (const float*)d_in[25];
  const float* lin_out_w = (const float*)d_in[26];
  const float* lin_out_b = (const float*)d_in[27];
  float* outp = (float*)d_out;

  const size_t EH = (size_t)EDGES * HD;
  float* buf0 = (float*)d_ws;                    // x_ji
  float* buf1 = buf0 + EH;                       // x_kj
  float* buf2 = buf1 + EH;                       // h
  float* sbfp = buf2 + EH;                       // sbf_h sorted [T,8]
  float* wt   = sbfp + (size_t)TRIP * NBIL;      // [1024,128]
  float* fend = wt + (size_t)NBIL * HD * HD;
  int* offs   = (int*)fend;                      // E+1 (alloc E+4 for alignment)
  int* cursor = offs + (EDGES + 4);
  int* gkj    = cursor + EDGES;
  int* tpos   = gkj + TRIP;
  int* blks   = tpos + TRIP;
  int* iend   = blks + 256;
  const size_t base_bytes = (size_t)((char*)iend - (char*)d_ws);
  const size_t moff = (base_bytes + 255) & ~(size_t)255;
  float* Mbuf = (float*)((char*)d_ws + moff);
  long ce = 0;
  if ((long)ws_size > (long)moff) {
    ce = ((long)ws_size - (long)moff) / (1024 * 4);
    ce &= ~127L;
    if (ce > 250112) ce = 250112;     // one chunk covers all edges (rounded to 128)
  }
  const bool split = (ce >= 8192);

  hipMemsetAsync(cursor, 0, EDGES * sizeof(int), stream);
  const int TB  = (TRIP + 255) / 256;
  const int SCB = (EDGES + 1023) / 1024;
  k_hist<<<TB, 256, 0, stream>>>(idx_ji, cursor);
  k_scan1<<<SCB, 256, 0, stream>>>(cursor, blks);
  k_scan2<<<1, 256, 0, stream>>>(blks, SCB);
  k_scan3<<<SCB, 256, 0, stream>>>(cursor, blks, offs);
  k_scatter<<<TB, 256, 0, stream>>>(idx_ji, idx_kj, cursor, gkj, tpos);
  k_wt<<<(NBIL * HD * HD + 255) / 256, 256, 0, stream>>>(Wtri, wt);
  k_sbfh<<<TB, 256, 0, stream>>>(sbf, lin_sbf_w, tpos, sbfp);
  k_edge<<<(EDGES + 31) / 32, 256, 0, stream>>>(x, rbf, lin_rbf_w,
      lin_ji_w, lin_ji_b, lin_kj_w, lin_kj_b, buf0, buf1);

  if (split) {
    for (long c0 = 0; c0 < EDGES; c0 += ce) {
      const int ecount = (int)((EDGES - c0 < ce) ? (EDGES - c0) : ce);
      k_mA<<<(ecount + 3) / 4, 256, 0, stream>>>(buf1, sbfp, gkj, offs, Mbuf, (int)c0, ecount);
      k_mB<<<(ecount + 127) / 128, 256, 0, stream>>>(Mbuf, wt, buf0, buf2, (int)c0, ecount);
    }
  } else {
    k_m<<<EDGES / 16, 256, 0, stream>>>(buf1, sbfp, gkj, offs, wt, buf0, buf2);
  }

  const int GB = (EDGES + 63) / 64;
  k_res<<<GB, 256, 0, stream>>>(buf2, rb_w1, rb_b1, rb_w2, rb_b2, buf0);       // h1
  k_gemm<true ><<<GB, 256, 0, stream>>>(buf0, lin_w, lin_b, x, buf1);          // h2 = silu(..)+x
  k_res<<<GB, 256, 0, stream>>>(buf1, ra1_w1, ra1_b1, ra1_w2, ra1_b2, buf2);   // h3
  k_res<<<GB, 256, 0, stream>>>(buf2, ra2_w1, ra2_b1, ra2_w2, ra2_b2, buf0);   // h4
  k_gemm<false><<<GB, 256, 0, stream>>>(buf0, lin_out_w, lin_out_b, nullptr, outp);
}